// Round 3
// baseline (805.643 us; speedup 1.0000x reference)
//
#include <hip/hip_runtime.h>
#include <math.h>

// Problem constants (from reference setup_inputs):
// B=8 images, N=256*256 px/image, P=200 prototypes, C=20 classes.
constexpr int B = 8;
constexpr int N = 256 * 256;
constexpr int P = 200;
constexpr int C = 20;
constexpr int NSLOT = B * C;     // 160 (image,class) slots
constexpr int GRID = (B * N) / 256;  // 2048 blocks, exactly 1 px/thread

// ---------------------------------------------------------------------------
// Kernel 1: zero the global accumulators + completion ticket (d_ws is
// poisoned 0xAA before every launch, so this must run every call).
// ---------------------------------------------------------------------------
__global__ __launch_bounds__(256) void zero_kernel(float* __restrict__ ws_acc,
                                                   int* __restrict__ done) {
  const int t = threadIdx.x;
  for (int i = t; i < 2 * NSLOT; i += 256) ws_acc[i] = 0.0f;
  if (t == 0) *done = 0;
}

// ---------------------------------------------------------------------------
// Kernel 2: fused main pass + last-block final reduction.
//  - per-block: analyze prototype_class_identity (16 KB, L2-hot) -> per-class
//    contiguous weight-1 run descriptor; fast iff all classes qualify
//    (true for the block-diagonal one-hot). General fallback reads ident
//    directly (slow path, correctness-only).
//  - per-pixel: read the 40-B prototype slice as float2s, accumulate
//    |a| into per-block LDS (image,class) slots.
//  - flush: one device-scope atomicAdd per nonzero slot per block.
//  - last block (ticket == gridDim-1): acquire-read accumulators, compute
//    class_norm mean, write the scalar.
// ---------------------------------------------------------------------------
__global__ __launch_bounds__(256) void fused_kernel(
    const float* __restrict__ A,       // [B*N, P]
    const int* __restrict__ labels,    // [B*N]
    const float* __restrict__ ident,   // [P, C]
    float* __restrict__ ws_acc,        // sums[NSLOT] then counts[NSLOT]
    int* __restrict__ done,
    float* __restrict__ out) {
  __shared__ float s_sum[NSLOT];
  __shared__ float s_cnt[NSLOT];
  __shared__ int s_start[C];
  __shared__ int s_len[C];
  __shared__ int s_okc[C];
  __shared__ int s_fast;
  __shared__ int s_ticket;
  __shared__ float s_pc[C];
  __shared__ float red_num[256];
  __shared__ float red_den[256];

  const int t = threadIdx.x;
  for (int i = t; i < NSLOT; i += 256) { s_sum[i] = 0.0f; s_cnt[i] = 0.0f; }

  // --- identity analysis (20 threads x 200 L2-cached loads) ---
  if (t < C) {
    int cnt = 0, first = -1, last = -1, uniform = 1;
    for (int p = 0; p < P; ++p) {
      const float v = ident[p * C + t];
      if (v != 0.0f) {
        if (first < 0) first = p;
        last = p;
        ++cnt;
        if (v != 1.0f) uniform = 0;
      }
    }
    s_start[t] = (first < 0) ? 0 : first;
    s_len[t] = cnt;
    s_okc[t] = (cnt == 0) || (uniform && (last - first + 1 == cnt));
  }
  __syncthreads();
  if (t == 0) {
    int ok = 1;
    for (int c = 0; c < C; ++c) ok &= s_okc[c];
    s_fast = ok;
  }
  __syncthreads();
  const int fast = s_fast;

  // --- pixel pass: exactly one pixel per thread ---
  const int i = blockIdx.x * 256 + t;
  if (i < B * N) {
    const int lab = labels[i] - 1;
    if (lab >= 0 && lab < C) {
      float s = 0.0f;
      if (fast) {
        const int p0 = s_start[lab];
        const int cnt = s_len[lab];
        const float* base = A + (size_t)i * P + p0;
        int k = 0;
        if ((p0 & 1) && k < cnt) { s += fabsf(base[k]); ++k; }  // 8-B align
        #pragma unroll 5
        for (; k + 1 < cnt; k += 2) {
          const float2 v = *(const float2*)(base + k);
          s += fabsf(v.x) + fabsf(v.y);
        }
        if (k < cnt) s += fabsf(base[k]);
      } else {
        // general fallback: weighted over the full column (L2-cached ident)
        const float* row = A + (size_t)i * P;
        for (int p = 0; p < P; ++p) {
          const float w = ident[p * C + lab];
          if (w != 0.0f) s += fabsf(row[p]) * w;
        }
      }
      const int slot = (i / N) * C + lab;
      atomicAdd(&s_sum[slot], s);
      atomicAdd(&s_cnt[slot], 1.0f);
    }
  }
  __syncthreads();

  // --- flush per-block partials (device-scope atomics) ---
  for (int j = t; j < NSLOT; j += 256) {
    const float cv = s_cnt[j];
    if (cv != 0.0f) {
      atomicAdd(&ws_acc[j], s_sum[j]);
      atomicAdd(&ws_acc[NSLOT + j], cv);
    }
  }

  // --- completion ticket (release: fence before increment) ---
  __threadfence();
  __syncthreads();
  if (t == 0) s_ticket = atomicAdd(done, 1);
  __syncthreads();
  if (s_ticket != (int)gridDim.x - 1) return;

  // --- last block: final reduction ---
  __threadfence();  // acquire side
  if (t < C) {
    float s = 0.0f;
    for (int p = 0; p < P; ++p) s += ident[p * C + t];
    s_pc[t] = s;
  }
  __syncthreads();
  float num = 0.0f, den = 0.0f;
  for (int j = t; j < NSLOT; j += 256) {
    const float cnt = __hip_atomic_load(&ws_acc[NSLOT + j], __ATOMIC_RELAXED,
                                        __HIP_MEMORY_SCOPE_AGENT);
    const float sm = __hip_atomic_load(&ws_acc[j], __ATOMIC_RELAXED,
                                       __HIP_MEMORY_SCOPE_AGENT);
    const float p = s_pc[j % C];
    if (cnt > 0.0f && p > 0.0f) {
      num += sm / fmaxf(cnt, 1.0f) / fmaxf(p, 1.0f);
      den += 1.0f;
    }
  }
  red_num[t] = num;
  red_den[t] = den;
  __syncthreads();
  for (int s = 128; s > 0; s >>= 1) {
    if (t < s) { red_num[t] += red_num[t + s]; red_den[t] += red_den[t + s]; }
    __syncthreads();
  }
  if (t == 0) out[0] = red_num[0] / fmaxf(red_den[0], 1.0f);
}

extern "C" void kernel_launch(void* const* d_in, const int* in_sizes, int n_in,
                              void* d_out, int out_size, void* d_ws, size_t ws_size,
                              hipStream_t stream) {
  const float* A      = (const float*)d_in[0];   // [B, N, P] fp32
  const int*   labels = (const int*)d_in[1];     // [B, H, W] int
  const float* ident  = (const float*)d_in[2];   // [P, C] fp32
  float* out = (float*)d_out;

  float* ws_acc = (float*)d_ws;              // 2*NSLOT floats
  int*   done   = (int*)(ws_acc + 2 * NSLOT);

  zero_kernel<<<1, 256, 0, stream>>>(ws_acc, done);
  fused_kernel<<<GRID, 256, 0, stream>>>(A, labels, ident, ws_acc, done, out);
}